// Round 4
// baseline (626.370 us; speedup 1.0000x reference)
//
#include <hip/hip_runtime.h>
#include <hip/hip_bf16.h>
#include <math.h>

#define B_    32
#define T_    512
#define D_    512
#define P_    200
#define NP_   8
#define N_TOT (P_*NP_)     // 1600
#define NEG_  (-100000.0f)

__device__ __forceinline__ float wave_reduce_sum(float v) {
#pragma unroll
  for (int off = 32; off; off >>= 1) v += __shfl_xor(v, off, 64);
  return v;
}

// ---------------- normalize x rows: xn[b,t,:] = x / max(||x||, 1e-12) ----------------
__global__ __launch_bounds__(256) void norm_x_kernel(const float* __restrict__ x,
                                                     float* __restrict__ xn) {
  int row  = blockIdx.x * 4 + (threadIdx.x >> 6);   // 0..16383
  int lane = threadIdx.x & 63;
  const float* xr = x + (size_t)row * D_;
  float4 v0 = *(const float4*)(xr + lane * 4);
  float4 v1 = *(const float4*)(xr + 256 + lane * 4);
  float s = v0.x*v0.x + v0.y*v0.y + v0.z*v0.z + v0.w*v0.w
          + v1.x*v1.x + v1.y*v1.y + v1.z*v1.z + v1.w*v1.w;
  s = wave_reduce_sum(s);
  float dn = fmaxf(sqrtf(s), 1e-12f);
  float* xo = xn + (size_t)row * D_;
  float4 o0 = make_float4(v0.x/dn, v0.y/dn, v0.z/dn, v0.w/dn);
  float4 o1 = make_float4(v1.x/dn, v1.y/dn, v1.z/dn, v1.w/dn);
  *(float4*)(xo + lane * 4) = o0;
  *(float4*)(xo + 256 + lane * 4) = o1;
}

// ------- normalize prototypes over d and transpose to wt[n=p*8+i][d] -------
__global__ __launch_bounds__(256) void norm_w_kernel(const float* __restrict__ proto,
                                                     float* __restrict__ wt) {
  int n    = blockIdx.x * 4 + (threadIdx.x >> 6);   // 0..1599
  int lane = threadIdx.x & 63;
  int p = n >> 3, i = n & 7;
  float v[8];
  float s = 0.f;
#pragma unroll
  for (int k = 0; k < 8; k++) {
    int d = k * 64 + lane;
    v[k] = proto[((size_t)p * D_ + d) * NP_ + i];
    s += v[k] * v[k];
  }
  s = wave_reduce_sum(s);
  float dn = fmaxf(sqrtf(s), 1e-12f);
  float* wo = wt + (size_t)n * D_;
#pragma unroll
  for (int k = 0; k < 8; k++) wo[k * 64 + lane] = v[k] / dn;
}

// ------------- f32 GEMM: dist[b][n][t] = sum_d wt[n][d] * xn[b][t][d] -------------
// 128(n) x 128(t) tile per WG, BK=32, 256 threads, 8x8 micro-tile (split 4+4).
#define BK 32
__global__ __launch_bounds__(256) void gemm_kernel(const float* __restrict__ xn,
                                                   const float* __restrict__ wt,
                                                   const float* __restrict__ tm,
                                                   float* __restrict__ dist) {
  __shared__ float As[BK][132];   // [kk][n_local]  (pad 132 -> bank (4kk+n)%32)
  __shared__ float Xs[BK][132];   // [kk][t_local]
  int b  = blockIdx.z;
  int t0 = blockIdx.x * 128;
  int n0 = blockIdx.y * 128;
  int tid = threadIdx.x;
  int tx = tid & 15, ty = tid >> 4;
  const float* xb = xn + (size_t)b * T_ * D_;

  float acc[8][8];
#pragma unroll
  for (int u = 0; u < 8; u++)
#pragma unroll
    for (int v = 0; v < 8; v++) acc[u][v] = 0.f;

  int lr = tid >> 3;   // 0..31 row group
  int lc = tid & 7;    // k-offset group (lc*4)

  for (int k0 = 0; k0 < D_; k0 += BK) {
    float4 aw[4], xw[4];
#pragma unroll
    for (int l = 0; l < 4; l++) {
      int r = lr + l * 32;
      int n = n0 + r; if (n > N_TOT - 1) n = N_TOT - 1;   // clamp (stores guarded)
      aw[l] = *(const float4*)(wt + (size_t)n * D_ + k0 + lc * 4);
      xw[l] = *(const float4*)(xb + (size_t)(t0 + r) * D_ + k0 + lc * 4);
    }
    __syncthreads();
#pragma unroll
    for (int l = 0; l < 4; l++) {
      int r = lr + l * 32;
      As[lc*4+0][r] = aw[l].x; As[lc*4+1][r] = aw[l].y;
      As[lc*4+2][r] = aw[l].z; As[lc*4+3][r] = aw[l].w;
      Xs[lc*4+0][r] = xw[l].x; Xs[lc*4+1][r] = xw[l].y;
      Xs[lc*4+2][r] = xw[l].z; Xs[lc*4+3][r] = xw[l].w;
    }
    __syncthreads();
#pragma unroll
    for (int kk = 0; kk < BK; kk++) {
      float4 a0 = *(const float4*)&As[kk][ty * 4];
      float4 a1 = *(const float4*)&As[kk][64 + ty * 4];
      float4 x0 = *(const float4*)&Xs[kk][tx * 4];
      float4 x1 = *(const float4*)&Xs[kk][64 + tx * 4];
      float av[8] = {a0.x, a0.y, a0.z, a0.w, a1.x, a1.y, a1.z, a1.w};
      float xv[8] = {x0.x, x0.y, x0.z, x0.w, x1.x, x1.y, x1.z, x1.w};
#pragma unroll
      for (int u = 0; u < 8; u++)
#pragma unroll
        for (int v = 0; v < 8; v++) acc[u][v] = fmaf(av[u], xv[v], acc[u][v]);
    }
  }

  // epilogue: apply timeline mask, store as dist[b][n][t]
  float4 tm0 = *(const float4*)(tm + b * T_ + t0 + tx * 4);
  float4 tm1 = *(const float4*)(tm + b * T_ + t0 + 64 + tx * 4);
  float tmv[8] = {tm0.x, tm0.y, tm0.z, tm0.w, tm1.x, tm1.y, tm1.z, tm1.w};
#pragma unroll
  for (int u = 0; u < 8; u++) {
    int r = (u < 4) ? (ty * 4 + u) : (64 + ty * 4 + (u - 4));
    int n = n0 + r;
    if (n < N_TOT) {
      float* dr = dist + ((size_t)b * N_TOT + n) * T_ + t0;
      float o[8];
#pragma unroll
      for (int v = 0; v < 8; v++) o[v] = acc[u][v] * tmv[v] + (1.0f - tmv[v]) * NEG_;
      *(float4*)(dr + tx * 4)      = make_float4(o[0], o[1], o[2], o[3]);
      *(float4*)(dr + 64 + tx * 4) = make_float4(o[4], o[5], o[6], o[7]);
    }
  }
}

// --------------- greedy selection, one wave per (b,p) pair ---------------
__global__ __launch_bounds__(256) void select_kernel(const float* __restrict__ dist,
                                                     const float* __restrict__ psel,
                                                     float* __restrict__ out) {
  __shared__ float sd[4][NP_][T_];   // 64 KiB
  int w    = threadIdx.x >> 6;
  int lane = threadIdx.x & 63;
  int pair = blockIdx.x * 4 + w;     // 0..6399
  int b = pair / P_;
  int p = pair % P_;
  const float* dbase = dist + ((size_t)b * N_TOT + p * NP_) * T_;
#pragma unroll
  for (int i = 0; i < NP_; i++) {
    *(float4*)&sd[w][i][lane * 4]       = *(const float4*)(dbase + (size_t)i * T_ + lane * 4);
    *(float4*)&sd[w][i][256 + lane * 4] = *(const float4*)(dbase + (size_t)i * T_ + 256 + lane * 4);
  }
  __syncthreads();   // cross-lane LDS visibility (cheap: one barrier per block)

  int ev[8]; int sid[8]; float vals[8];
  unsigned msub = 0xFFu;
  int e_last = 0;
#pragma unroll
  for (int it = 0; it < 8; ++it) {
    float best_v = -3.0e38f; int best_t = 0; int best_i = 0;
    for (int i = 0; i < 8; i++) {
      bool sub_ok = ((msub >> i) & 1u) != 0u;
      float lv = -3.0e38f; int lt = 0;
#pragma unroll
      for (int c = 0; c < 8; c++) {
        int t = c * 64 + lane;
        float dv = sd[w][i][t];
        bool ok = sub_ok;
        if (it > 0) {
          int dtt = t - e_last;
          ok = ok && (dtt <= 3) && (dtt >= -3);
          if (it > 1) ok = ok && (dtt > 0);
        }
#pragma unroll
        for (int k = 0; k < 8; k++)
          if (k < it && t == ev[k]) ok = false;
        float dm = ok ? dv : (dv + NEG_);   // matches ref's dist + (1-m)*NEG in f32
        if (dm > lv) { lv = dm; lt = t; }   // c ascending => first-t on ties per lane
      }
      // cross-lane: max value, tie -> smallest t (matches jnp.argmax first-index)
#pragma unroll
      for (int off = 32; off > 0; off >>= 1) {
        float ov = __shfl_xor(lv, off, 64);
        int   ot = __shfl_xor(lt, off, 64);
        if (ov > lv || (ov == lv && ot < lt)) { lv = ov; lt = ot; }
      }
      if (lv > best_v) { best_v = lv; best_t = lt; best_i = i; }  // strict > => first-i ties
    }
    vals[it] = best_v; ev[it] = best_t; sid[it] = best_i;
    msub &= ~(1u << best_i);
    e_last = best_t;
  }

  if (lane == 0) {
    // stable argsort of sid (key = sid*8 + original index)
    int ord[8]; unsigned used = 0;
#pragma unroll
    for (int j = 0; j < 8; j++) {
      int bk = 1 << 30, bi = 0;
#pragma unroll
      for (int k = 0; k < 8; k++)
        if (!((used >> k) & 1u)) { int key = sid[k] * 8 + k; if (key < bk) { bk = key; bi = k; } }
      ord[j] = bi; used |= 1u << bi;
    }
    float slots[8]; float ssum = 0.f;
#pragma unroll
    for (int i = 0; i < 8; i++) {
      slots[i] = 1.0f / (1.0f + expf(-psel[p * NP_ + i]));
      ssum += slots[i];
    }
    float fac = ssum + 1e-10f;
    float acc = 0.f;
#pragma unroll
    for (int j = 0; j < 8; j++) acc += vals[ord[j]] * (slots[j] * 8.0f / fac);
    int bp = b * P_ + p;
    out[bp] = acc;
    out[B_ * P_ + bp] = 8.0f - acc;
#pragma unroll
    for (int j = 0; j < 8; j++) out[2 * B_ * P_ + bp * 8 + j] = (float)ev[ord[j]];
  }
}

extern "C" void kernel_launch(void* const* d_in, const int* in_sizes, int n_in,
                              void* d_out, int out_size, void* d_ws, size_t ws_size,
                              hipStream_t stream) {
  const float* x     = (const float*)d_in[0];
  const float* tm    = (const float*)d_in[1];
  const float* proto = (const float*)d_in[2];
  const float* psel  = (const float*)d_in[3];
  float* out = (float*)d_out;
  float* ws  = (float*)d_ws;

  float* xn   = ws;                                  // 8,388,608 floats
  float* wt   = xn + (size_t)B_ * T_ * D_;           //   819,200 floats
  float* dist = wt + (size_t)N_TOT * D_;             // 26,214,400 floats
  // total ws need: 141,688,832 bytes

  norm_x_kernel<<<dim3(B_ * T_ / 4), 256, 0, stream>>>(x, xn);
  norm_w_kernel<<<dim3(N_TOT / 4), 256, 0, stream>>>(proto, wt);
  gemm_kernel<<<dim3(T_ / 128, (N_TOT + 127) / 128, B_), 256, 0, stream>>>(xn, wt, tm, dist);
  select_kernel<<<dim3(B_ * P_ / 4), 256, 0, stream>>>(dist, psel, out);
}

// Round 5
// 252.057 us; speedup vs baseline: 2.4850x; 2.4850x over previous
//
#include <hip/hip_runtime.h>
#include <hip/hip_bf16.h>
#include <hip/hip_fp16.h>
#include <math.h>

#define B_    32
#define T_    512
#define D_    512
#define P_    200
#define NP_   8
#define N_TOT 1600
#define NEG_  (-100000.0f)
#define LO_SCALE 2048.0f
#define LO_INV   (1.0f/2048.0f)

typedef __attribute__((ext_vector_type(8))) _Float16 f16x8;
typedef __attribute__((ext_vector_type(4))) _Float16 f16x4;
typedef __attribute__((ext_vector_type(4))) float   f32x4;

// global -> LDS direct copy, 16B per lane; LDS dest = wave-uniform base + lane*16
#define GLL16(gp, lp) __builtin_amdgcn_global_load_lds( \
    (const __attribute__((address_space(1))) void*)(gp), \
    (__attribute__((address_space(3))) void*)(lp), 16, 0, 0)

__device__ __forceinline__ float wave_reduce_sum(float v) {
#pragma unroll
  for (int off = 32; off; off >>= 1) v += __shfl_xor(v, off, 64);
  return v;
}

// ---- normalize x rows; emit fp16 split: xh = f16(x/n), xl = f16((x/n - xh)*2^11) ----
__global__ __launch_bounds__(256) void norm_x_kernel(const float* __restrict__ x,
                                                     _Float16* __restrict__ xh,
                                                     _Float16* __restrict__ xl) {
  int row  = blockIdx.x * 4 + (threadIdx.x >> 6);   // 0..16383
  int lane = threadIdx.x & 63;
  const float* xr = x + (size_t)row * D_;
  float4 v0 = *(const float4*)(xr + lane * 4);
  float4 v1 = *(const float4*)(xr + 256 + lane * 4);
  float s = v0.x*v0.x + v0.y*v0.y + v0.z*v0.z + v0.w*v0.w
          + v1.x*v1.x + v1.y*v1.y + v1.z*v1.z + v1.w*v1.w;
  s = wave_reduce_sum(s);
  float dn = fmaxf(sqrtf(s), 1e-12f);
  float f[8] = {v0.x/dn, v0.y/dn, v0.z/dn, v0.w/dn, v1.x/dn, v1.y/dn, v1.z/dn, v1.w/dn};
  f16x4 h0, h1, l0, l1;
#pragma unroll
  for (int j = 0; j < 4; j++) {
    h0[j] = (_Float16)f[j];
    l0[j] = (_Float16)((f[j] - (float)h0[j]) * LO_SCALE);
    h1[j] = (_Float16)f[4 + j];
    l1[j] = (_Float16)((f[4 + j] - (float)h1[j]) * LO_SCALE);
  }
  size_t base = (size_t)row * D_;
  *(f16x4*)(xh + base + lane * 4)       = h0;
  *(f16x4*)(xh + base + 256 + lane * 4) = h1;
  *(f16x4*)(xl + base + lane * 4)       = l0;
  *(f16x4*)(xl + base + 256 + lane * 4) = l1;
}

// ---- normalize prototypes over d, transpose to [n][d], fp16 split ----
__global__ __launch_bounds__(256) void norm_w_kernel(const float* __restrict__ proto,
                                                     _Float16* __restrict__ wh,
                                                     _Float16* __restrict__ wl) {
  int n    = blockIdx.x * 4 + (threadIdx.x >> 6);   // 0..1599
  int lane = threadIdx.x & 63;
  int p = n >> 3, i = n & 7;
  float v[8];
  float s = 0.f;
#pragma unroll
  for (int k = 0; k < 8; k++) {
    int d = k * 64 + lane;
    v[k] = proto[((size_t)p * D_ + d) * NP_ + i];
    s += v[k] * v[k];
  }
  s = wave_reduce_sum(s);
  float dn = fmaxf(sqrtf(s), 1e-12f);
  size_t base = (size_t)n * D_;
#pragma unroll
  for (int k = 0; k < 8; k++) {
    float f = v[k] / dn;
    _Float16 h = (_Float16)f;
    wh[base + k * 64 + lane] = h;
    wl[base + k * 64 + lane] = (_Float16)((f - (float)h) * LO_SCALE);
  }
}

// ---- fp16-split MFMA GEMM: dist[b][n][t] = sum_d w[n][d] x[b][t][d], + timeline mask ----
// 128(n) x 128(t) tile, BK=32, 4 waves each 64x64 (4x4 frags of 16x16x32).
// acc_h = xh*wh ; acc_c = xh*wl' + xl'*wh ; result = acc_h + acc_c/2048.
__global__ __launch_bounds__(256, 2) void gemm_mfma(
    const _Float16* __restrict__ XH, const _Float16* __restrict__ XL,
    const _Float16* __restrict__ WH, const _Float16* __restrict__ WL,
    const float* __restrict__ tm, float* __restrict__ dist) {
  __shared__ _Float16 lds[4 * 128 * 32];   // Ah | Al | Xh | Xl, each [128][32], 32 KiB
  const int b = blockIdx.z;
  const int n0 = blockIdx.y * 128;
  const int t0 = blockIdx.x * 128;
  const int tid = threadIdx.x;
  const int w = tid >> 6, l = tid & 63;

  // staging: per array 512 chunks of 16B; wave w covers chunks (w*2+j)*64 + lane
  int c0 = (w * 2 + 0) * 64 + l;
  int c1 = (w * 2 + 1) * 64 + l;
  int r0 = c0 >> 2, kc0 = (c0 & 3) * 8;
  int r1 = c1 >> 2, kc1 = (c1 & 3) * 8;
  int an0 = n0 + r0; if (an0 > N_TOT - 1) an0 = N_TOT - 1;  // clamp; stores guarded
  int an1 = n0 + r1; if (an1 > N_TOT - 1) an1 = N_TOT - 1;
  const _Float16* wh0 = WH + (size_t)an0 * D_ + kc0;
  const _Float16* wh1 = WH + (size_t)an1 * D_ + kc1;
  const _Float16* wl0 = WL + (size_t)an0 * D_ + kc0;
  const _Float16* wl1 = WL + (size_t)an1 * D_ + kc1;
  const _Float16* xh0 = XH + ((size_t)b * T_ + t0 + r0) * D_ + kc0;
  const _Float16* xh1 = XH + ((size_t)b * T_ + t0 + r1) * D_ + kc1;
  const _Float16* xl0 = XL + ((size_t)b * T_ + t0 + r0) * D_ + kc0;
  const _Float16* xl1 = XL + ((size_t)b * T_ + t0 + r1) * D_ + kc1;
  _Float16* ldAh = lds +     0 + (w * 2) * 512;
  _Float16* ldAl = lds +  4096 + (w * 2) * 512;
  _Float16* ldXh = lds +  8192 + (w * 2) * 512;
  _Float16* ldXl = lds + 12288 + (w * 2) * 512;

  const int wn = (w >> 1) * 64, wtf = (w & 1) * 64;
  const int fr = l & 15, fq = l >> 4;

  f32x4 acch[4][4], accc[4][4];
#pragma unroll
  for (int m = 0; m < 4; m++)
#pragma unroll
    for (int n = 0; n < 4; n++) { acch[m][n] = (f32x4)0.0f; accc[m][n] = (f32x4)0.0f; }

  for (int k0 = 0; k0 < D_; k0 += 32) {
    GLL16(wh0 + k0, ldAh);
    GLL16(wh1 + k0, ldAh + 512);
    GLL16(wl0 + k0, ldAl);
    GLL16(wl1 + k0, ldAl + 512);
    GLL16(xh0 + k0, ldXh);
    GLL16(xh1 + k0, ldXh + 512);
    GLL16(xl0 + k0, ldXl);
    GLL16(xl1 + k0, ldXl + 512);
    __syncthreads();
    f16x8 ah[4], al[4], bh[4], bl[4];
#pragma unroll
    for (int m = 0; m < 4; m++) {
      int ro = (wn + m * 16 + fr) * 32 + fq * 8;
      ah[m] = *(const f16x8*)&lds[ro];
      al[m] = *(const f16x8*)&lds[4096 + ro];
    }
#pragma unroll
    for (int n = 0; n < 4; n++) {
      int ro = (wtf + n * 16 + fr) * 32 + fq * 8;
      bh[n] = *(const f16x8*)&lds[8192 + ro];
      bl[n] = *(const f16x8*)&lds[12288 + ro];
    }
#pragma unroll
    for (int m = 0; m < 4; m++)
#pragma unroll
      for (int n = 0; n < 4; n++) {
        acch[m][n] = __builtin_amdgcn_mfma_f32_16x16x32_f16(ah[m], bh[n], acch[m][n], 0, 0, 0);
        accc[m][n] = __builtin_amdgcn_mfma_f32_16x16x32_f16(ah[m], bl[n], accc[m][n], 0, 0, 0);
        accc[m][n] = __builtin_amdgcn_mfma_f32_16x16x32_f16(al[m], bh[n], accc[m][n], 0, 0, 0);
      }
    __syncthreads();
  }

  // epilogue: combine, timeline mask, store.  C/D: col = lane&15, row = (lane>>4)*4 + reg
#pragma unroll
  for (int n = 0; n < 4; n++) {
    int col = t0 + wtf + n * 16 + fr;
    float tmc = tm[b * T_ + col];
#pragma unroll
    for (int m = 0; m < 4; m++) {
      int nb = n0 + wn + m * 16 + fq * 4;
#pragma unroll
      for (int r = 0; r < 4; r++) {
        int nr = nb + r;
        if (nr < N_TOT) {
          float v = acch[m][n][r] + accc[m][n][r] * LO_INV;
          v = v * tmc + (1.0f - tmc) * NEG_;
          dist[((size_t)b * N_TOT + nr) * T_ + col] = v;
        }
      }
    }
  }
}

// ---- greedy selection, one wave per (b,p); windowed shortcut when tm==1 ----
__global__ __launch_bounds__(256) void select_kernel(const float* __restrict__ dist,
                                                     const float* __restrict__ tmg,
                                                     const float* __restrict__ psel,
                                                     float* __restrict__ out) {
  __shared__ float sd[4][NP_][T_];   // 64 KiB
  int w = threadIdx.x >> 6, lane = threadIdx.x & 63;
  int pair = blockIdx.x * 4 + w;
  int b = pair / P_, p = pair % P_;
  const float* dbase = dist + ((size_t)b * N_TOT + p * NP_) * T_;
#pragma unroll
  for (int i = 0; i < NP_; i++) {
    *(float4*)&sd[w][i][lane * 4]       = *(const float4*)(dbase + (size_t)i * T_ + lane * 4);
    *(float4*)&sd[w][i][256 + lane * 4] = *(const float4*)(dbase + (size_t)i * T_ + 256 + lane * 4);
  }
  bool okt = true;
#pragma unroll
  for (int c = 0; c < 8; c++) okt = okt && (tmg[b * T_ + c * 64 + lane] == 1.0f);
  bool tmones = (__ballot(okt) == ~0ULL);   // fast path valid only for all-ones mask
  __syncthreads();

  // history in registers, static-indexed (avoid scratch)
  float valh[8]; int evh[8], sidh[8];
#pragma unroll
  for (int k = 0; k < 8; k++) { valh[k] = 0.f; evh[k] = -1; sidh[k] = 0; }
  unsigned msub = 0xFFu;
  int e_last = 0;

  for (int it = 0; it < 8; ++it) {
    float bv = 0.f; int bkey = 0;
    bool done = false;
    if (tmones && it > 0) {
      // window: it==1: e0 +/- 3 (7 slots); it>=2: (e,e+3] (3 slots).  lane = i*8+widx
      int i = lane >> 3, widx = lane & 7;
      int tw, nw;
      if (it == 1) { tw = e_last - 3 + widx; nw = 7; }
      else         { tw = e_last + 1 + widx; nw = 3; }
      bool valid = (widx < nw) && (tw >= 0) && (tw < T_) && (((msub >> i) & 1u) != 0u);
#pragma unroll
      for (int k = 0; k < 8; k++) if (tw == evh[k]) valid = false;
      float v  = valid ? sd[w][i][tw] : -3.0e38f;
      int  key = valid ? (i * T_ + tw) : 0x7FFFFFFF;
#pragma unroll
      for (int off = 32; off; off >>= 1) {
        float ov = __shfl_xor(v, off, 64);
        int  ok2 = __shfl_xor(key, off, 64);
        if (ov > v || (ov == v && ok2 < key)) { v = ov; key = ok2; }
      }
      if (v > -2.9e38f) { bv = v; bkey = key; done = true; }
      // else: window empty -> everything penalized uniformly; general scan below
      // computes exactly dist+NEG argmax (active set is empty), matching the ref.
    }
    if (!done) {
      // general path: active = sub_ok && adjacency(direction) && not previously selected
      float lv = -3.0e38f; int lkey = 0x7FFFFFFF;
      for (int i = 0; i < 8; i++) {
        bool sub_ok = ((msub >> i) & 1u) != 0u;
#pragma unroll
        for (int c = 0; c < 8; c++) {
          int t = c * 64 + lane;
          bool act = sub_ok;
          if (it > 0) {
            int dt = t - e_last;
            act = act && (dt <= 3) && (dt >= -3);
            if (it > 1) act = act && (dt > 0);
          }
#pragma unroll
          for (int k = 0; k < 8; k++) if (t == evh[k]) act = false;
          float dv = sd[w][i][t];
          float dm = act ? dv : (dv + NEG_);   // exact ref arithmetic (f32 quantized ties)
          if (dm > lv) { lv = dm; lkey = i * T_ + t; }   // per-lane scan is (i,t)-ascending
        }
      }
#pragma unroll
      for (int off = 32; off; off >>= 1) {
        float ov = __shfl_xor(lv, off, 64);
        int  ok2 = __shfl_xor(lkey, off, 64);
        if (ov > lv || (ov == lv && ok2 < lkey)) { lv = ov; lkey = ok2; }
      }
      bv = lv; bkey = lkey;
    }
    int bi = bkey >> 9, bt = bkey & (T_ - 1);
#pragma unroll
    for (int k = 0; k < 8; k++) {   // static-index history update
      if (it == k) { valh[k] = bv; evh[k] = bt; sidh[k] = bi; }
    }
    msub &= ~(1u << bi);
    e_last = bt;
  }

  if (lane == 0) {
    int ord[8]; unsigned used = 0;
#pragma unroll
    for (int j = 0; j < 8; j++) {    // stable argsort of sidh
      int bk = 1 << 30, bi2 = 0;
#pragma unroll
      for (int k = 0; k < 8; k++)
        if (!((used >> k) & 1u)) { int key = sidh[k] * 8 + k; if (key < bk) { bk = key; bi2 = k; } }
      ord[j] = bi2; used |= 1u << bi2;
    }
    float slots[8]; float ssum = 0.f;
#pragma unroll
    for (int i = 0; i < 8; i++) {
      slots[i] = 1.0f / (1.0f + expf(-psel[p * NP_ + i]));
      ssum += slots[i];
    }
    float fac = ssum + 1e-10f;
    float acc = 0.f;
    float vr[8]; float er[8];
#pragma unroll
    for (int j = 0; j < 8; j++) {
      float vv = 0.f, ee = 0.f;
#pragma unroll
      for (int k = 0; k < 8; k++) if (ord[j] == k) { vv = valh[k]; ee = (float)evh[k]; }
      vr[j] = vv; er[j] = ee;
    }
#pragma unroll
    for (int j = 0; j < 8; j++) acc += vr[j] * (slots[j] * 8.0f / fac);
    int bp = b * P_ + p;
    out[bp] = acc;
    out[B_ * P_ + bp] = 8.0f - acc;
#pragma unroll
    for (int j = 0; j < 8; j++) out[2 * B_ * P_ + bp * 8 + j] = er[j];
  }
}

extern "C" void kernel_launch(void* const* d_in, const int* in_sizes, int n_in,
                              void* d_out, int out_size, void* d_ws, size_t ws_size,
                              hipStream_t stream) {
  const float* x     = (const float*)d_in[0];
  const float* tm    = (const float*)d_in[1];
  const float* proto = (const float*)d_in[2];
  const float* psel  = (const float*)d_in[3];
  float* out = (float*)d_out;

  char* wsb = (char*)d_ws;
  _Float16* XH = (_Float16*)wsb;                             // 16,777,216 B
  _Float16* XL = (_Float16*)(wsb + 16777216u);               // 16,777,216 B
  _Float16* WH = (_Float16*)(wsb + 2u * 16777216u);          //  1,638,400 B
  _Float16* WL = (_Float16*)(wsb + 2u * 16777216u + 1638400u);
  float*   dist = (float*)(wsb + 2u * 16777216u + 2u * 1638400u);   // 104,857,600 B
  // total = 141,688,832 B (same footprint as the passing f32 version)

  norm_x_kernel<<<dim3(B_ * T_ / 4), 256, 0, stream>>>(x, XH, XL);
  norm_w_kernel<<<dim3(N_TOT / 4), 256, 0, stream>>>(proto, WH, WL);
  gemm_mfma<<<dim3(T_ / 128, (N_TOT + 127) / 128, B_), 256, 0, stream>>>(XH, XL, WH, WL, tm, dist);
  select_kernel<<<dim3(B_ * P_ / 4), 256, 0, stream>>>(dist, tm, psel, out);
}